// Round 1
// baseline (10846.103 us; speedup 1.0000x reference)
//
#include <hip/hip_runtime.h>

// Problem constants (from reference)
#define NBATCH 256
#define LI 2
#define LH 150
#define LQ 10
#define HS 128
#define WSD 128
#define KIT 40
#define AOUT 5

// LDS plane: 128x128 interior + 1-pixel zero halo, width padded to 132
#define LROWS 130
#define LCOLS 132
#define PLANE (LROWS * LCOLS)

// ---- Prep: collapse hidden layer.  W_eff[i,ky,kx] = sum_h r_w[h]*h_w[h,i,ky,kx],
//      b_eff = sum_h r_w[h]*h_b[h].  fp64 accumulation -> reorder error ~1e-7.
__global__ void prep_weff(const float* __restrict__ h_w,
                          const float* __restrict__ h_b,
                          const float* __restrict__ r_w,
                          float* __restrict__ w_eff) {
  const int t = threadIdx.x;
  if (t < 18) {
    const int i = t / 9, k = t % 9;
    double s = 0.0;
    for (int h = 0; h < LH; ++h)
      s += (double)r_w[h] * (double)h_w[(h * LI + i) * 9 + k];
    w_eff[t] = (float)s;
  } else if (t == 18) {
    double s = 0.0;
    for (int h = 0; h < LH; ++h)
      s += (double)r_w[h] * (double)h_b[h];
    w_eff[18] = (float)s;
  }
}

// Load a 6x6 neighborhood (top-left at p) with vectorized LDS reads.
// p is 16B-aligned because y0*LCOLS + x0 is a multiple of 4 words.
__device__ __forceinline__ void load_nb6(const float* __restrict__ p, float nb[6][6]) {
#pragma unroll
  for (int r = 0; r < 6; ++r) {
    const float* row = p + r * LCOLS;
    const float4 a = *reinterpret_cast<const float4*>(row);
    const float2 b = *reinterpret_cast<const float2*>(row + 4);
    nb[r][0] = a.x; nb[r][1] = a.y; nb[r][2] = a.z; nb[r][3] = a.w;
    nb[r][4] = b.x; nb[r][5] = b.y;
  }
}

// One block per batch item; 1024 threads; each thread owns a 4x4 output tile.
// LDS: r-plane + v-plane (137 KB) -> 1 block/CU, 16 waves.
__global__ __launch_bounds__(1024)
void vin_main(const float* __restrict__ input,
              const int* __restrict__ coords,
              const float* __restrict__ q_w,
              const float* __restrict__ w_in,
              const float* __restrict__ fc_w,
              const float* __restrict__ w_eff,
              float* __restrict__ out) {
  extern __shared__ float lds[];
  float* rs = lds;           // r plane [LROWS][LCOLS], zero halo
  float* vs = lds + PLANE;   // v plane

  const int b = blockIdx.x;
  const int tid = threadIdx.x;
  const int ty = tid >> 5;          // 0..31
  const int tx = tid & 31;          // 0..31
  const int y0 = ty << 2;           // output rows y0..y0+3
  const int x0 = tx << 2;           // output cols x0..x0+3
  const int nb_off = y0 * LCOLS + x0;  // top-left of 6x6 window (halo-inclusive)

  // zero both planes (establishes the zero-padding halo)
  for (int i = tid; i < 2 * PLANE; i += 1024) lds[i] = 0.0f;
  __syncthreads();

  // stage input: ch0 -> rs interior, ch1 -> vs interior (coalesced)
  const float* in0 = input + (size_t)b * (LI * HS * WSD);
  const float* in1 = in0 + HS * WSD;
  for (int i = tid; i < HS * WSD; i += 1024) {
    const int y = i >> 7, x = i & (WSD - 1);
    rs[(y + 1) * LCOLS + (x + 1)] = in0[i];
    vs[(y + 1) * LCOLS + (x + 1)] = in1[i];
  }
  __syncthreads();

  // ---- r = conv(input, W_eff, pad=1) + b_eff ----
  float racc[4][4];
  {
    float nb0[6][6], nb1[6][6];
    load_nb6(rs + nb_off, nb0);
    load_nb6(vs + nb_off, nb1);
    const float beff = w_eff[18];
#pragma unroll
    for (int dy = 0; dy < 4; ++dy)
#pragma unroll
      for (int dx = 0; dx < 4; ++dx) racc[dy][dx] = beff;
#pragma unroll
    for (int kk = 0; kk < 9; ++kk) {
      const int ky = kk / 3, kx = kk % 3;
      const float w0 = w_eff[kk];
      const float w1 = w_eff[9 + kk];
#pragma unroll
      for (int dy = 0; dy < 4; ++dy)
#pragma unroll
        for (int dx = 0; dx < 4; ++dx)
          racc[dy][dx] += w0 * nb0[dy + ky][dx + kx] + w1 * nb1[dy + ky][dx + kx];
    }
  }
  __syncthreads();  // all input reads done before overwriting rs
#pragma unroll
  for (int dy = 0; dy < 4; ++dy)
#pragma unroll
    for (int dx = 0; dx < 4; ++dx)
      rs[(y0 + dy + 1) * LCOLS + (x0 + dx + 1)] = racc[dy][dx];
  __syncthreads();

  // r-neighborhood is invariant across all VI iterations: hold it in registers.
  float nbr[6][6];
  load_nb6(rs + nb_off, nbr);

  // ---- v0 = max_c conv(r, q_w[c]) ----
  {
    float vmax[4][4];
#pragma unroll
    for (int dy = 0; dy < 4; ++dy)
#pragma unroll
      for (int dx = 0; dx < 4; ++dx) vmax[dy][dx] = -__builtin_inff();
#pragma unroll 1
    for (int c = 0; c < LQ; ++c) {
      float acc[4][4];
      const float wq0 = q_w[c * 9];
#pragma unroll
      for (int dy = 0; dy < 4; ++dy)
#pragma unroll
        for (int dx = 0; dx < 4; ++dx)
          acc[dy][dx] = wq0 * nbr[dy][dx];
#pragma unroll
      for (int kk = 1; kk < 9; ++kk) {
        const int ky = kk / 3, kx = kk % 3;
        const float wq = q_w[c * 9 + kk];
#pragma unroll
        for (int dy = 0; dy < 4; ++dy)
#pragma unroll
          for (int dx = 0; dx < 4; ++dx)
            acc[dy][dx] += wq * nbr[dy + ky][dx + kx];
      }
#pragma unroll
      for (int dy = 0; dy < 4; ++dy)
#pragma unroll
        for (int dx = 0; dx < 4; ++dx)
          vmax[dy][dx] = fmaxf(vmax[dy][dx], acc[dy][dx]);
    }
    // safe to overwrite vs: last vs reads were before the pre-r-write barrier
#pragma unroll
    for (int dy = 0; dy < 4; ++dy)
#pragma unroll
      for (int dx = 0; dx < 4; ++dx)
        vs[(y0 + dy + 1) * LCOLS + (x0 + dx + 1)] = vmax[dy][dx];
  }
  __syncthreads();

  // ---- K-1 = 39 value-iteration steps ----
#pragma unroll 1
  for (int it = 0; it < KIT - 1; ++it) {
    float nbv[6][6];
    load_nb6(vs + nb_off, nbv);
    float vmax[4][4];
#pragma unroll
    for (int dy = 0; dy < 4; ++dy)
#pragma unroll
      for (int dx = 0; dx < 4; ++dx) vmax[dy][dx] = -__builtin_inff();
#pragma unroll 1
    for (int c = 0; c < LQ; ++c) {
      float acc[4][4];
      const float wq0 = q_w[c * 9];
      const float wv0 = w_in[c * 9];
#pragma unroll
      for (int dy = 0; dy < 4; ++dy)
#pragma unroll
        for (int dx = 0; dx < 4; ++dx)
          acc[dy][dx] = wq0 * nbr[dy][dx] + wv0 * nbv[dy][dx];
#pragma unroll
      for (int kk = 1; kk < 9; ++kk) {
        const int ky = kk / 3, kx = kk % 3;
        const float wq = q_w[c * 9 + kk];
        const float wv = w_in[c * 9 + kk];
#pragma unroll
        for (int dy = 0; dy < 4; ++dy)
#pragma unroll
          for (int dx = 0; dx < 4; ++dx)
            acc[dy][dx] += wq * nbr[dy + ky][dx + kx] + wv * nbv[dy + ky][dx + kx];
      }
#pragma unroll
      for (int dy = 0; dy < 4; ++dy)
#pragma unroll
        for (int dx = 0; dx < 4; ++dx)
          vmax[dy][dx] = fmaxf(vmax[dy][dx], acc[dy][dx]);
    }
    __syncthreads();  // all reads of vs done
#pragma unroll
    for (int dy = 0; dy < 4; ++dy)
#pragma unroll
      for (int dx = 0; dx < 4; ++dx)
        vs[(y0 + dy + 1) * LCOLS + (x0 + dx + 1)] = vmax[dy][dx];
    __syncthreads();  // writes visible to next iteration
  }

  // ---- epilogue: final q at (sx,sy) only, then logits = fc_w @ q ----
  if (tid == 0) {
    const int sx = coords[b * 4 + 0];  // H index
    const int sy = coords[b * 4 + 1];  // W index
    const float* rb = rs + sx * LCOLS + sy;  // 3x3 window top-left (halo math)
    const float* vb = vs + sx * LCOLS + sy;
    float qv[LQ];
#pragma unroll 1
    for (int c = 0; c < LQ; ++c) {
      float s = 0.0f;
#pragma unroll
      for (int kk = 0; kk < 9; ++kk) {
        const int ky = kk / 3, kx = kk % 3;
        s += q_w[c * 9 + kk] * rb[ky * LCOLS + kx] +
             w_in[c * 9 + kk] * vb[ky * LCOLS + kx];
      }
      qv[c] = s;
    }
#pragma unroll 1
    for (int a = 0; a < AOUT; ++a) {
      float s = 0.0f;
#pragma unroll
      for (int c = 0; c < LQ; ++c) s += fc_w[a * LQ + c] * qv[c];
      out[b * AOUT + a] = s;
    }
  }
}

extern "C" void kernel_launch(void* const* d_in, const int* in_sizes, int n_in,
                              void* d_out, int out_size, void* d_ws, size_t ws_size,
                              hipStream_t stream) {
  const float* input = (const float*)d_in[0];   // (B, 2, 128, 128)
  const int*   coords = (const int*)d_in[1];    // (B, 4)
  const float* h_w = (const float*)d_in[2];     // (150, 2, 3, 3)
  const float* h_b = (const float*)d_in[3];     // (150,)
  const float* r_w = (const float*)d_in[4];     // (1, 150, 1, 1)
  const float* q_w = (const float*)d_in[5];     // (10, 1, 3, 3)
  const float* w_in = (const float*)d_in[6];    // (10, 1, 3, 3)
  const float* fc_w = (const float*)d_in[7];    // (5, 10)
  float* out = (float*)d_out;                   // (B, 5)
  float* w_eff = (float*)d_ws;                  // 19 floats scratch

  const size_t smem = (size_t)2 * PLANE * sizeof(float);  // 137,280 B (>64KB)
  hipFuncSetAttribute(reinterpret_cast<const void*>(vin_main),
                      hipFuncAttributeMaxDynamicSharedMemorySize, (int)smem);

  prep_weff<<<1, 64, 0, stream>>>(h_w, h_b, r_w, w_eff);
  vin_main<<<NBATCH, 1024, smem, stream>>>(input, coords, q_w, w_in, fc_w, w_eff, out);
}

// Round 2
// 1180.169 us; speedup vs baseline: 9.1903x; 9.1903x over previous
//
#include <hip/hip_runtime.h>

// Problem constants (from reference)
#define NBATCH 256
#define LI 2
#define LH 150
#define LQ 10
#define HS 128
#define WSD 128
#define KIT 40
#define AOUT 5

// LDS plane: 128x128 interior + 1-pixel zero halo, width padded to 132.
// Interior pixel (y,x) lives at lds[(y+1)*LCOLS + (x+1)].
#define LROWS 130
#define LCOLS 132
#define PLANE (LROWS * LCOLS)

// ---- Prep: collapse the linear hidden layer.
// W_eff[i,ky,kx] = sum_h r_w[h]*h_w[h,i,ky,kx],  b_eff = sum_h r_w[h]*h_b[h].
// fp64 accumulation -> reorder error ~1e-7, far under threshold.
__global__ void prep_weff(const float* __restrict__ h_w,
                          const float* __restrict__ h_b,
                          const float* __restrict__ r_w,
                          float* __restrict__ w_eff) {
  const int t = threadIdx.x;
  if (t < 18) {
    const int i = t / 9, k = t % 9;
    double s = 0.0;
    for (int h = 0; h < LH; ++h)
      s += (double)r_w[h] * (double)h_w[(h * LI + i) * 9 + k];
    w_eff[t] = (float)s;
  } else if (t == 18) {
    double s = 0.0;
    for (int h = 0; h < LH; ++h)
      s += (double)r_w[h] * (double)h_b[h];
    w_eff[18] = (float)s;
  }
}

// Load a 6-wide row (16B-aligned base) with vectorized LDS reads.
__device__ __forceinline__ void load_row6(const float* __restrict__ p, float row[6]) {
  const float4 a = *reinterpret_cast<const float4*>(p);
  const float2 b = *reinterpret_cast<const float2*>(p + 4);
  row[0] = a.x; row[1] = a.y; row[2] = a.z; row[3] = a.w;
  row[4] = b.x; row[5] = b.y;
}

__device__ __forceinline__ void load_nb6(const float* __restrict__ p, float nb[6][6]) {
#pragma unroll
  for (int r = 0; r < 6; ++r) load_row6(p + r * LCOLS, nb[r]);
}

// One block per batch item; 1024 threads; each thread owns a 4x4 output tile.
// LDS: r-plane + v-plane (137 KB) -> 1 block/CU, 16 waves (4 waves/SIMD).
// __launch_bounds__(1024, 4): 4 waves/EU min -> 128-VGPR cap. LDS already
// forces 1 block/CU, so this costs nothing and prevents the round-1 spill
// disaster (64-VGPR cap -> 37 GB of scratch traffic).
__global__ __launch_bounds__(1024, 4)
void vin_main(const float* __restrict__ input,
              const int* __restrict__ coords,
              const float* __restrict__ q_w,
              const float* __restrict__ w_in,
              const float* __restrict__ fc_w,
              const float* __restrict__ w_eff,
              float* __restrict__ out) {
  extern __shared__ float lds[];
  float* rs = lds;           // r plane [LROWS][LCOLS], zero halo
  float* vs = lds + PLANE;   // v plane

  const int b = blockIdx.x;
  const int tid = threadIdx.x;
  const int ty = tid >> 5;             // 0..31
  const int tx = tid & 31;             // 0..31
  const int y0 = ty << 2;              // output rows y0..y0+3
  const int x0 = tx << 2;              // output cols x0..x0+3
  const int nb_off = y0 * LCOLS + x0;  // 6x6 window top-left (16B-aligned)

  // zero both planes (establishes the zero-padding halo)
  for (int i = tid; i < 2 * PLANE; i += 1024) lds[i] = 0.0f;
  __syncthreads();

  // stage input: ch0 -> rs interior, ch1 -> vs interior (coalesced)
  const float* in0 = input + (size_t)b * (LI * HS * WSD);
  const float* in1 = in0 + HS * WSD;
  for (int i = tid; i < HS * WSD; i += 1024) {
    const int y = i >> 7, x = i & (WSD - 1);
    rs[(y + 1) * LCOLS + (x + 1)] = in0[i];
    vs[(y + 1) * LCOLS + (x + 1)] = in1[i];
  }
  __syncthreads();

  // ---- r = conv(input, W_eff, pad=1) + b_eff ----
  float racc[4][4];
  {
    float nb0[6][6], nb1[6][6];
    load_nb6(rs + nb_off, nb0);
    load_nb6(vs + nb_off, nb1);
    const float beff = w_eff[18];
#pragma unroll
    for (int dy = 0; dy < 4; ++dy)
#pragma unroll
      for (int dx = 0; dx < 4; ++dx) racc[dy][dx] = beff;
#pragma unroll
    for (int kk = 0; kk < 9; ++kk) {
      const int ky = kk / 3, kx = kk % 3;
      const float w0 = w_eff[kk];
      const float w1 = w_eff[9 + kk];
#pragma unroll
      for (int dy = 0; dy < 4; ++dy)
#pragma unroll
        for (int dx = 0; dx < 4; ++dx)
          racc[dy][dx] += w0 * nb0[dy + ky][dx + kx] + w1 * nb1[dy + ky][dx + kx];
    }
  }
  __syncthreads();  // all input reads done before overwriting rs
#pragma unroll
  for (int dy = 0; dy < 4; ++dy)
#pragma unroll
    for (int dx = 0; dx < 4; ++dx)
      rs[(y0 + dy + 1) * LCOLS + (x0 + dx + 1)] = racc[dy][dx];
  __syncthreads();

  // r-neighborhood is invariant across all VI iterations: hold in registers
  // (36 VGPRs, persistent).
  float nbr[6][6];
  load_nb6(rs + nb_off, nbr);

  // ---- v0 = max_c conv(r, q_w[c]) ---- (register-only compute from nbr)
  {
    float outv[4][4];
#pragma unroll
    for (int dy = 0; dy < 4; ++dy)
#pragma unroll
      for (int dx = 0; dx < 4; ++dx) outv[dy][dx] = -__builtin_inff();
#pragma unroll 2
    for (int c = 0; c < LQ; ++c) {
      const float* qc = q_w + c * 9;
#pragma unroll
      for (int dy = 0; dy < 4; ++dy) {
        float acc[4];
#pragma unroll
        for (int dx = 0; dx < 4; ++dx) acc[dx] = qc[0] * nbr[dy][dx];
#pragma unroll
        for (int kk = 1; kk < 9; ++kk) {
          const int ky = kk / 3, kx = kk % 3;
          const float q = qc[kk];
#pragma unroll
          for (int dx = 0; dx < 4; ++dx) acc[dx] += q * nbr[dy + ky][dx + kx];
        }
#pragma unroll
        for (int dx = 0; dx < 4; ++dx)
          outv[dy][dx] = fmaxf(outv[dy][dx], acc[dx]);
      }
    }
    // vs (input ch1) fully consumed before the pre-r-write barrier
#pragma unroll
    for (int dy = 0; dy < 4; ++dy)
#pragma unroll
      for (int dx = 0; dx < 4; ++dx)
        vs[(y0 + dy + 1) * LCOLS + (x0 + dx + 1)] = outv[dy][dx];
  }
  __syncthreads();

  // ---- K-1 = 39 value-iteration steps ----
  // Rolling 3-row v-window (18 regs) instead of full 6x6 (36): keeps peak
  // register demand ~90, under the 128 cap -> no scratch spill.
#pragma unroll 1
  for (int it = 0; it < KIT - 1; ++it) {
    const float* vp = vs + nb_off;
    float va[6], vb[6], vc[6];
    load_row6(vp, va);
    load_row6(vp + LCOLS, vb);
    float outv[4][4];
#pragma unroll
    for (int dy = 0; dy < 4; ++dy) {
      load_row6(vp + (dy + 2) * LCOLS, vc);
#pragma unroll
      for (int dx = 0; dx < 4; ++dx) outv[dy][dx] = -__builtin_inff();
#pragma unroll 2
      for (int c = 0; c < LQ; ++c) {
        const float* qc = q_w + c * 9;
        const float* wc = w_in + c * 9;
        float acc[4];
#pragma unroll
        for (int dx = 0; dx < 4; ++dx) acc[dx] = qc[0] * nbr[dy][dx];
#pragma unroll
        for (int kk = 1; kk < 9; ++kk) {
          const int ky = kk / 3, kx = kk % 3;
          const float q = qc[kk];
#pragma unroll
          for (int dx = 0; dx < 4; ++dx) acc[dx] += q * nbr[dy + ky][dx + kx];
        }
#pragma unroll
        for (int kk = 0; kk < 9; ++kk) {
          const int ky = kk / 3, kx = kk % 3;
          const float w = wc[kk];
          const float* vrow = (ky == 0) ? va : (ky == 1) ? vb : vc;
#pragma unroll
          for (int dx = 0; dx < 4; ++dx) acc[dx] += w * vrow[dx + kx];
        }
#pragma unroll
        for (int dx = 0; dx < 4; ++dx)
          outv[dy][dx] = fmaxf(outv[dy][dx], acc[dx]);
      }
      // rotate window (SSA-renamed away under full dy unroll)
#pragma unroll
      for (int j = 0; j < 6; ++j) { va[j] = vb[j]; vb[j] = vc[j]; }
    }
    __syncthreads();  // all reads of vs done
#pragma unroll
    for (int dy = 0; dy < 4; ++dy)
#pragma unroll
      for (int dx = 0; dx < 4; ++dx)
        vs[(y0 + dy + 1) * LCOLS + (x0 + dx + 1)] = outv[dy][dx];
    __syncthreads();  // writes visible to next iteration
  }

  // ---- epilogue: final q at (sx,sy) only, then logits = fc_w @ q ----
  if (tid == 0) {
    const int sx = coords[b * 4 + 0];  // H index
    const int sy = coords[b * 4 + 1];  // W index
    const float* rb = rs + sx * LCOLS + sy;  // 3x3 window top-left (halo math)
    const float* vb2 = vs + sx * LCOLS + sy;
    float qv[LQ];
#pragma unroll 1
    for (int c = 0; c < LQ; ++c) {
      float s = 0.0f;
#pragma unroll
      for (int kk = 0; kk < 9; ++kk) {
        const int ky = kk / 3, kx = kk % 3;
        s += q_w[c * 9 + kk] * rb[ky * LCOLS + kx] +
             w_in[c * 9 + kk] * vb2[ky * LCOLS + kx];
      }
      qv[c] = s;
    }
#pragma unroll 1
    for (int a = 0; a < AOUT; ++a) {
      float s = 0.0f;
#pragma unroll
      for (int c = 0; c < LQ; ++c) s += fc_w[a * LQ + c] * qv[c];
      out[b * AOUT + a] = s;
    }
  }
}

extern "C" void kernel_launch(void* const* d_in, const int* in_sizes, int n_in,
                              void* d_out, int out_size, void* d_ws, size_t ws_size,
                              hipStream_t stream) {
  const float* input = (const float*)d_in[0];   // (B, 2, 128, 128)
  const int*   coords = (const int*)d_in[1];    // (B, 4)
  const float* h_w = (const float*)d_in[2];     // (150, 2, 3, 3)
  const float* h_b = (const float*)d_in[3];     // (150,)
  const float* r_w = (const float*)d_in[4];     // (1, 150, 1, 1)
  const float* q_w = (const float*)d_in[5];     // (10, 1, 3, 3)
  const float* w_in = (const float*)d_in[6];    // (10, 1, 3, 3)
  const float* fc_w = (const float*)d_in[7];    // (5, 10)
  float* out = (float*)d_out;                   // (B, 5)
  float* w_eff = (float*)d_ws;                  // 19 floats scratch

  const size_t smem = (size_t)2 * PLANE * sizeof(float);  // 137,280 B (>64KB)
  hipFuncSetAttribute(reinterpret_cast<const void*>(vin_main),
                      hipFuncAttributeMaxDynamicSharedMemorySize, (int)smem);

  prep_weff<<<1, 64, 0, stream>>>(h_w, h_b, r_w, w_eff);
  vin_main<<<NBATCH, 1024, smem, stream>>>(input, coords, q_w, w_in, fc_w, w_eff, out);
}